// Round 1
// baseline (1171.833 us; speedup 1.0000x reference)
//
#include <hip/hip_runtime.h>
#include <hip/hip_bf16.h>

#define DIM   256
#define LSEQ  32768
#define HEADS 8
#define DHEAD 64
#define HID   512
#define GROUPS 32
#define CPG   8
#define EPS   1e-5f

// ---- workspace layout (float offsets) ----
#define WS_GSUM   0                              // 32
#define WS_GSUMSQ 32                             // 32
#define WS_S      64                             // 8*64*64 = 32768 (unnormalized context)
#define WS_Z      (64 + HEADS*DHEAD*DHEAD)       // 512 (softmax denominators)
#define WS_ZEROED (WS_Z + HID)                   // 33344 floats zeroed each launch
#define WS_A      WS_ZEROED                      // 256  per-channel scale
#define WS_BB     (WS_A + DIM)                   // 256  per-channel offset
#define WS_BE     (WS_BB + DIM)                  // 1536 folded qkv bias (row-indexed)
#define WS_WET    (WS_BE + 1536)                 // 1024*256 folded k/v weights, [c][r]
#define WS_C      (WS_WET + 1024*DIM)            // 32768 normalized context
#define WS_W2     (WS_C + HEADS*DHEAD*DHEAD)     // 256*512  w_out folded with context
#define WS_W3T    (WS_W2 + DIM*HID)              // 256*256  final folded weight, [c][d]
#define WS_B3     (WS_W3T + DIM*DIM)             // 256
#define WS_TOTAL  (WS_B3 + DIM)                  // 527168 floats ~= 2.1 MB

#define CW   64     // sequence-chunk width per block
#define EKS  68     // ek LDS row stride (floats)  -> bank-conflict-free
#define VS   68     // v  LDS row stride (bf16)

static __device__ __forceinline__ float bf2f(__hip_bfloat16 h) { return __bfloat162float(h); }

// ---------------- group stats: per-channel row sums -> atomic per-group ----------------
__global__ void k_stats(const float* __restrict__ x, float* __restrict__ ws) {
    const int ch = blockIdx.x;            // 256 channels, one per block
    const int g  = ch >> 3;
    const float4* xp = (const float4*)(x + (size_t)ch * LSEQ);
    float s = 0.f, s2 = 0.f;
    for (int i = threadIdx.x; i < LSEQ/4; i += 256) {
        float4 v = xp[i];
        s  += v.x + v.y + v.z + v.w;
        s2 += v.x*v.x + v.y*v.y + v.z*v.z + v.w*v.w;
    }
    for (int off = 32; off > 0; off >>= 1) { s += __shfl_down(s, off); s2 += __shfl_down(s2, off); }
    __shared__ float red[8];
    int lane = threadIdx.x & 63, w = threadIdx.x >> 6;
    if (lane == 0) { red[w] = s; red[4+w] = s2; }
    __syncthreads();
    if (threadIdx.x == 0) {
        float S  = red[0]+red[1]+red[2]+red[3];
        float S2 = red[4]+red[5]+red[6]+red[7];
        atomicAdd(&ws[WS_GSUM  + g], S);
        atomicAdd(&ws[WS_GSUMSQ+ g], S2);
    }
}

// ---------------- a[c], bb[c] from group stats ----------------
__global__ void k_ab(const float* __restrict__ gn_w, const float* __restrict__ gn_b,
                     float* __restrict__ ws) {
    int c = threadIdx.x;
    int g = c >> 3;
    const float inv_n = 1.f / (float)(CPG * LSEQ);
    float mu  = ws[WS_GSUM + g] * inv_n;
    float var = ws[WS_GSUMSQ + g] * inv_n - mu*mu;
    float inv = rsqrtf(var + EPS);
    float a = gn_w[c] * inv;
    ws[WS_A  + c] = a;
    ws[WS_BB + c] = gn_b[c] - mu * a;
}

// ---------------- fold k/v weights (transposed: WeT[c][r], r in [0,1024)) ----------------
__global__ void k_fold_w(const float* __restrict__ w_qkv, float* __restrict__ ws) {
    int idx = blockIdx.x * 256 + threadIdx.x;          // 65536 threads
    for (int i = idx; i < 1024*DIM; i += 65536) {
        int c = i >> 10, r = i & 1023;                  // r<512: k rows, r>=512: v rows
        ws[WS_WET + i] = w_qkv[(size_t)(512 + r) * DIM + c] * ws[WS_A + c];
    }
}

// ---------------- fold all 1536 qkv biases: be[r] = b_qkv[r] + dot(w_qkv[r], bb) ------
__global__ void k_fold_b(const float* __restrict__ w_qkv, const float* __restrict__ b_qkv,
                         float* __restrict__ ws) {
    int r = blockIdx.x * 256 + threadIdx.x;            // 1536 threads (6 blocks)
    float s = b_qkv[r];
    const float* wr = w_qkv + (size_t)r * DIM;
    for (int c = 0; c < DIM; c++) s += wr[c] * ws[WS_BB + c];
    ws[WS_BE + r] = s;
}

// ---------------- fused k/v GEMM + exp + context partial accumulation ----------------
// block: 64-column chunk of L. waves 0,1 compute k rows (32 each), waves 2,3 v rows.
__global__ __launch_bounds__(256) void k_main(const float* __restrict__ x, float* __restrict__ ws) {
    __shared__ __hip_bfloat16 xs[DIM*CW];    // 32 KB x tile (bf16)
    __shared__ float ek[DHEAD*EKS];          // 17 KB exp(k) tile
    __shared__ __hip_bfloat16 vs[DHEAD*VS];  // 8.5 KB v tile (bf16)
    const int tid  = threadIdx.x;
    const int col0 = blockIdx.x * CW;

    // stage x chunk (coalesced float4, store bf16)
    {
        const float4* x4 = (const float4*)x;
        int c4 = col0 >> 2;
        for (int i = tid; i < DIM*(CW/4); i += 256) {
            int row = i >> 4, q = i & 15;
            float4 v = x4[(size_t)row*(LSEQ/4) + c4 + q];
            int b = row*CW + q*4;
            xs[b+0] = __float2bfloat16(v.x); xs[b+1] = __float2bfloat16(v.y);
            xs[b+2] = __float2bfloat16(v.z); xs[b+3] = __float2bfloat16(v.w);
        }
    }
    __syncthreads();

    const int col = tid & 63;
    const int rq  = __builtin_amdgcn_readfirstlane(tid >> 6);   // wave id 0..3 (uniform)
    float* Sg = ws + WS_S;
    float* Zg = ws + WS_Z;
    const float* WeT = ws + WS_WET;
    const float* be  = ws + WS_BE;

    for (int h = 0; h < HEADS; h++) {
        // r-index into WeT: k rows [h*64, h*64+64), v rows [512+h*64, ...)
        const int base = (rq < 2) ? (h*64 + rq*32) : (512 + h*64 + (rq-2)*32);
        float acc[32];
        #pragma unroll
        for (int j = 0; j < 32; j++) acc[j] = 0.f;
        for (int c = 0; c < DIM; c++) {
            float xv = bf2f(xs[c*CW + col]);
            const float* w = WeT + c*1024 + base;   // uniform -> s_load_dwordx16
            #pragma unroll
            for (int j = 0; j < 32; j++) acc[j] += w[j] * xv;
        }
        __syncthreads();   // previous head's ek/vs readers are done
        if (rq < 2) {
            const int r0 = rq*32;
            #pragma unroll
            for (int j = 0; j < 32; j++)
                ek[(r0+j)*EKS + col] = __expf(acc[j] + be[512 + base + j]);
        } else {
            const int r0 = (rq-2)*32;
            #pragma unroll
            for (int j = 0; j < 32; j++)
                vs[(r0+j)*VS + col] = __float2bfloat16(acc[j] + be[512 + base + j]);
        }
        __syncthreads();

        // S[h][c][e] += sum_col ek[c][col] * v[e][col]; thread: c = 4*(tid>>4)+i, e = (tid&15)+16*jj
        {
            const int c0 = tid >> 4;
            const int e0 = tid & 15;
            float sacc[4][4];
            #pragma unroll
            for (int i=0;i<4;i++)
              #pragma unroll
              for (int jj=0;jj<4;jj++) sacc[i][jj] = 0.f;
            for (int cq = 0; cq < CW/4; cq++) {
                float4 e4[4];
                #pragma unroll
                for (int i = 0; i < 4; i++)
                    e4[i] = *(const float4*)&ek[(c0*4+i)*EKS + cq*4];
                float v4[4][4];
                #pragma unroll
                for (int jj = 0; jj < 4; jj++) {
                    ushort4 raw = *(const ushort4*)&vs[(e0+16*jj)*VS + cq*4];
                    v4[jj][0] = __uint_as_float((unsigned)raw.x << 16);
                    v4[jj][1] = __uint_as_float((unsigned)raw.y << 16);
                    v4[jj][2] = __uint_as_float((unsigned)raw.z << 16);
                    v4[jj][3] = __uint_as_float((unsigned)raw.w << 16);
                }
                #pragma unroll
                for (int i = 0; i < 4; i++)
                  #pragma unroll
                  for (int jj = 0; jj < 4; jj++)
                    sacc[i][jj] += e4[i].x*v4[jj][0] + e4[i].y*v4[jj][1]
                                 + e4[i].z*v4[jj][2] + e4[i].w*v4[jj][3];
            }
            #pragma unroll
            for (int i = 0; i < 4; i++)
              #pragma unroll
              for (int jj = 0; jj < 4; jj++)
                atomicAdd(&Sg[(h*64 + c0*4+i)*64 + e0 + 16*jj], sacc[i][jj]);
            if (tid < 64) {
                float z = 0.f;
                for (int cq = 0; cq < CW/4; cq++) {
                    float4 e4 = *(const float4*)&ek[tid*EKS + cq*4];
                    z += e4.x + e4.y + e4.z + e4.w;
                }
                atomicAdd(&Zg[h*64 + tid], z);
            }
        }
        // next iteration's compute phase touches only xs; the post-compute
        // __syncthreads() protects ek/vs against early overwrite.
    }
}

// ---------------- C = S / Z ----------------
__global__ void k_ctx(float* __restrict__ ws) {
    int idx = blockIdx.x * 256 + threadIdx.x;   // 32768
    ws[WS_C + idx] = ws[WS_S + idx] / ws[WS_Z + (idx >> 6)];
}

// ---------------- W2[d][hc] = sum_e w_out[d][h*64+e] * C[hc][e] ----------------
__global__ void k_w2(const float* __restrict__ w_out, float* __restrict__ ws) {
    int idx = blockIdx.x * 256 + threadIdx.x;   // 131072
    int d = idx >> 9, hc = idx & 511;
    int h64 = hc & ~63;
    const float* C = ws + WS_C;
    float s = 0.f;
    for (int e = 0; e < 64; e++)
        s += w_out[(size_t)d*HID + h64 + e] * C[hc*64 + e];
    ws[WS_W2 + idx] = s;
}

// ---------------- W3T[c][d] = a[c] * sum_hc W2[d][hc] * w_qkv[hc][c] ----------------
__global__ void k_w3t(const float* __restrict__ w_qkv, float* __restrict__ ws) {
    int d = blockIdx.x;
    int c = threadIdx.x;
    const float* W2 = ws + WS_W2 + (size_t)d*HID;
    float s = 0.f;
    for (int hc = 0; hc < HID; hc++)
        s += W2[hc] * w_qkv[(size_t)hc*DIM + c];
    ws[WS_W3T + c*DIM + d] = s * ws[WS_A + c];
}

// ---------------- b3[d] = b_out[d] + sum_hc W2[d][hc] * be_q[hc] ----------------
__global__ void k_b3(const float* __restrict__ b_out, float* __restrict__ ws) {
    int d = threadIdx.x;
    const float* W2 = ws + WS_W2 + (size_t)d*HID;
    const float* be = ws + WS_BE;            // rows 0..511 are the q biases
    float s = b_out[d];
    for (int hc = 0; hc < HID; hc++) s += W2[hc] * be[hc];
    ws[WS_B3 + d] = s;
}

// ---------------- final: out = W3 @ x + b3 ----------------
__global__ __launch_bounds__(256) void k_final(const float* __restrict__ x,
                                               const float* __restrict__ ws,
                                               float* __restrict__ out) {
    __shared__ float xs[DIM*CW];   // 64 KB
    const int tid  = threadIdx.x;
    const int col0 = blockIdx.x * CW;
    {
        const float4* x4 = (const float4*)x;
        int c4 = col0 >> 2;
        for (int i = tid; i < DIM*(CW/4); i += 256) {
            int row = i >> 4, q = i & 15;
            float4 v = x4[(size_t)row*(LSEQ/4) + c4 + q];
            *(float4*)&xs[row*CW + q*4] = v;
        }
    }
    __syncthreads();
    const int col   = tid & 63;
    const int rq    = __builtin_amdgcn_readfirstlane(tid >> 6);
    const int rbase = rq * 64;
    const float* W3T = ws + WS_W3T;
    float acc[64];
    #pragma unroll
    for (int j = 0; j < 64; j++) acc[j] = 0.f;
    for (int c = 0; c < DIM; c++) {
        float xv = xs[c*CW + col];
        const float* w = W3T + c*DIM + rbase;   // uniform -> s_load
        #pragma unroll
        for (int j = 0; j < 64; j++) acc[j] += w[j] * xv;
    }
    const float* b3 = ws + WS_B3 + rbase;
    #pragma unroll
    for (int j = 0; j < 64; j++)
        out[(size_t)(rbase + j)*LSEQ + col0 + col] = acc[j] + b3[j];
}

extern "C" void kernel_launch(void* const* d_in, const int* in_sizes, int n_in,
                              void* d_out, int out_size, void* d_ws, size_t ws_size,
                              hipStream_t stream) {
    const float* x     = (const float*)d_in[0];
    const float* gn_w  = (const float*)d_in[1];
    const float* gn_b  = (const float*)d_in[2];
    const float* w_qkv = (const float*)d_in[3];
    const float* b_qkv = (const float*)d_in[4];
    const float* w_out = (const float*)d_in[5];
    const float* b_out = (const float*)d_in[6];
    float* out = (float*)d_out;
    float* ws  = (float*)d_ws;

    hipMemsetAsync(ws, 0, WS_ZEROED * sizeof(float), stream);
    k_stats <<<DIM,      256, 0, stream>>>(x, ws);
    k_ab    <<<1,        256, 0, stream>>>(gn_w, gn_b, ws);
    k_fold_w<<<256,      256, 0, stream>>>(w_qkv, ws);
    k_fold_b<<<6,        256, 0, stream>>>(w_qkv, b_qkv, ws);
    k_main  <<<LSEQ/CW,  256, 0, stream>>>(x, ws);
    k_ctx   <<<128,      256, 0, stream>>>(ws);
    k_w2    <<<512,      256, 0, stream>>>(w_out, ws);
    k_w3t   <<<256,      256, 0, stream>>>(w_qkv, ws);
    k_b3    <<<1,        256, 0, stream>>>(b_out, ws);
    k_final <<<LSEQ/CW,  256, 0, stream>>>(x, ws, out);
}

// Round 2
// 325.089 us; speedup vs baseline: 3.6047x; 3.6047x over previous
//
#include <hip/hip_runtime.h>
#include <hip/hip_bf16.h>

typedef unsigned short ushort_t;
typedef unsigned int uint_t;

#define DIM   256
#define LSEQ  32768
#define HEADS 8
#define DHEAD 64
#define HID   512
#define CPG   8
#define EPS   1e-5f

typedef float f32x4 __attribute__((ext_vector_type(4)));
typedef short sfrag8 __attribute__((ext_vector_type(8)));

static __device__ __forceinline__ float b2f(ushort_t u) {
    return __uint_as_float((uint_t)u << 16);
}
static __device__ __forceinline__ ushort_t f2bs(float f) {
    union { __hip_bfloat16 h; ushort_t u; } cv;
    cv.h = __float2bfloat16(f);
    return cv.u;
}

// ======================= shared small kernels (pointer-parameterized) =======================

__global__ void k_stats(const float* __restrict__ x, float* __restrict__ gsum,
                        float* __restrict__ gsumsq) {
    const int ch = blockIdx.x;
    const int g  = ch >> 3;
    const float4* xp = (const float4*)(x + (size_t)ch * LSEQ);
    float s = 0.f, s2 = 0.f;
    for (int i = threadIdx.x; i < LSEQ/4; i += 256) {
        float4 v = xp[i];
        s  += v.x + v.y + v.z + v.w;
        s2 += v.x*v.x + v.y*v.y + v.z*v.z + v.w*v.w;
    }
    for (int off = 32; off > 0; off >>= 1) { s += __shfl_down(s, off); s2 += __shfl_down(s2, off); }
    __shared__ float red[8];
    int lane = threadIdx.x & 63, w = threadIdx.x >> 6;
    if (lane == 0) { red[w] = s; red[4+w] = s2; }
    __syncthreads();
    if (threadIdx.x == 0) {
        atomicAdd(&gsum[g],   red[0]+red[1]+red[2]+red[3]);
        atomicAdd(&gsumsq[g], red[4]+red[5]+red[6]+red[7]);
    }
}

__global__ void k_ab(const float* __restrict__ gn_w, const float* __restrict__ gn_b,
                     const float* __restrict__ gsum, const float* __restrict__ gsumsq,
                     float* __restrict__ A, float* __restrict__ BB) {
    int c = threadIdx.x;
    int g = c >> 3;
    const float inv_n = 1.f / (float)(CPG * LSEQ);
    float mu  = gsum[g] * inv_n;
    float var = gsumsq[g] * inv_n - mu*mu;
    float inv = rsqrtf(var + EPS);
    float a = gn_w[c] * inv;
    A[c]  = a;
    BB[c] = gn_b[c] - mu * a;
}

__global__ void k_fold_b(const float* __restrict__ w_qkv, const float* __restrict__ b_qkv,
                         const float* __restrict__ BB, float* __restrict__ BE) {
    int r = blockIdx.x * 256 + threadIdx.x;   // 1536
    float s = b_qkv[r];
    const float* wr = w_qkv + (size_t)r * DIM;
    for (int c = 0; c < DIM; c++) s += wr[c] * BB[c];
    BE[r] = s;
}

__global__ void k_ctx(const float* __restrict__ S, const float* __restrict__ Z,
                      float* __restrict__ C) {
    int idx = blockIdx.x * 256 + threadIdx.x;   // 32768
    C[idx] = S[idx] / Z[idx >> 6];
}

__global__ void k_w2(const float* __restrict__ w_out, const float* __restrict__ C,
                     float* __restrict__ W2) {
    int idx = blockIdx.x * 256 + threadIdx.x;   // 131072
    int d = idx >> 9, hc = idx & 511;
    int h64 = hc & ~63;
    float s = 0.f;
    for (int e = 0; e < 64; e++)
        s += w_out[(size_t)d*HID + h64 + e] * C[hc*64 + e];
    W2[idx] = s;
}

__global__ void k_b3(const float* __restrict__ b_out, const float* __restrict__ W2,
                     const float* __restrict__ BE, float* __restrict__ B3) {
    int d = threadIdx.x;
    const float* W2d = W2 + (size_t)d*HID;
    float s = b_out[d];
    for (int hc = 0; hc < HID; hc++) s += W2d[hc] * BE[hc];
    B3[d] = s;
}

// ======================= NEW MFMA path =======================

// transpose x (fp32 [c][l]) -> xT (bf16 [l][c])
__global__ __launch_bounds__(256) void k_tr(const float* __restrict__ x,
                                            ushort_t* __restrict__ XT) {
    __shared__ ushort_t tile[64 * 258];    // stride 258 shorts: write conflicts ~2-way
    const int tid = threadIdx.x;
    const int ln  = tid & 63;
    const int wv  = tid >> 6;
    const int l0  = blockIdx.x * 64;
    for (int p = 0; p < 64; p++) {
        int c = wv * 64 + p;
        float v = x[(size_t)c * LSEQ + l0 + ln];
        tile[ln * 258 + c] = f2bs(v);
    }
    __syncthreads();
    const int lrow = tid >> 2;
    const int cseg = (tid & 3) * 64;
    const uint_t* tp = (const uint_t*)&tile[lrow * 258 + cseg];
    uint_t* dst = (uint_t*)(XT + (size_t)(l0 + lrow) * 256 + cseg);
    #pragma unroll
    for (int g = 0; g < 8; g++) {
        uint_t a = tp[g*4+0], b = tp[g*4+1], c = tp[g*4+2], d = tp[g*4+3];
        uint4 v4; v4.x = a; v4.y = b; v4.z = c; v4.w = d;
        *(uint4*)(dst + g*4) = v4;
    }
}

// WeB bf16 [r'][c], r' = h*128 + part*64 + j ; part0 = k rows (orig 512+h*64+j), part1 = v rows
// also BE2[r'] reordered kv biases
__global__ void k_fold_w_new(const float* __restrict__ w_qkv, const float* __restrict__ A,
                             const float* __restrict__ BE,
                             ushort_t* __restrict__ WEB, float* __restrict__ BE2) {
    int idx = blockIdx.x * 256 + threadIdx.x;   // 262144
    int rp = idx >> 8, c = idx & 255;
    int h = rp >> 7, sub = rp & 127, part = sub >> 6, j = sub & 63;
    int orig = 512 + part * 512 + h * 64 + j;
    WEB[(size_t)rp * 256 + c] = f2bs(w_qkv[(size_t)orig * 256 + c] * A[c]);
    if (c == 0) BE2[rp] = BE[orig];
}

// fused kv-GEMM + exp + context GEMM (all MFMA)
// grid: (L/256) chunks x 8 heads. block 256 = 4 waves.
__global__ __launch_bounds__(256) void k_attn(const ushort_t* __restrict__ XT,
                                              const ushort_t* __restrict__ WEB,
                                              const float* __restrict__ BE2,
                                              float* __restrict__ S, float* __restrict__ Z) {
    __shared__ ushort_t ek[64 * 136];   // exp(k) tile, stride 136 shorts (272 B, 16B-aligned rows)
    __shared__ ushort_t vv[64 * 136];   // v tile
    const int tid  = threadIdx.x;
    const int lane = tid & 63;
    const int wv   = __builtin_amdgcn_readfirstlane(tid >> 6);
    const int q    = lane >> 4;
    const int ln   = lane & 15;
    const int h    = blockIdx.x & 7;
    const int l0   = (blockIdx.x >> 3) * 256;

    const ushort_t* Ah  = WEB + (size_t)(h * 128) * 256;
    const ushort_t* a0p = Ah + (size_t)(32 * wv + ln) * 256 + q * 8;
    const ushort_t* a1p = a0p + 16 * 256;

    // biases for this wave's 32 rows (per-lane by q, per-reg r, per m-tile i)
    float bias[2][4];
    #pragma unroll
    for (int i = 0; i < 2; i++)
        #pragma unroll
        for (int r = 0; r < 4; r++)
            bias[i][r] = BE2[h * 128 + 32 * wv + 16 * i + q * 4 + r];

    f32x4 Sacc[4];
    #pragma unroll
    for (int nt = 0; nt < 4; nt++)
        #pragma unroll
        for (int e = 0; e < 4; e++) Sacc[nt][e] = 0.f;
    float zsum = 0.f;

    for (int s = 0; s < 2; s++) {
        const int l0s = l0 + s * 128;
        const ushort_t* Bb = XT + (size_t)l0s * 256;

        f32x4 acc[2][8];
        #pragma unroll
        for (int i = 0; i < 2; i++)
            #pragma unroll
            for (int nt = 0; nt < 8; nt++)
                #pragma unroll
                for (int e = 0; e < 4; e++) acc[i][nt][e] = 0.f;

        #pragma unroll
        for (int k0 = 0; k0 < 256; k0 += 32) {
            sfrag8 a0 = *(const sfrag8*)(a0p + k0);
            sfrag8 a1 = *(const sfrag8*)(a1p + k0);
            #pragma unroll
            for (int nt = 0; nt < 8; nt++) {
                sfrag8 b = *(const sfrag8*)(Bb + (size_t)(nt * 16 + ln) * 256 + k0 + q * 8);
                acc[0][nt] = __builtin_amdgcn_mfma_f32_16x16x32_bf16(a0, b, acc[0][nt], 0, 0, 0);
                acc[1][nt] = __builtin_amdgcn_mfma_f32_16x16x32_bf16(a1, b, acc[1][nt], 0, 0, 0);
            }
        }

        __syncthreads();   // previous sub-chunk's GEMM2/Z readers are done
        if (wv < 2) {
            #pragma unroll
            for (int i = 0; i < 2; i++)
                #pragma unroll
                for (int nt = 0; nt < 8; nt++)
                    #pragma unroll
                    for (int r = 0; r < 4; r++) {
                        int row = 32 * wv + 16 * i + q * 4 + r;
                        ek[row * 136 + nt * 16 + ln] = f2bs(__expf(acc[i][nt][r] + bias[i][r]));
                    }
        } else {
            #pragma unroll
            for (int i = 0; i < 2; i++)
                #pragma unroll
                for (int nt = 0; nt < 8; nt++)
                    #pragma unroll
                    for (int r = 0; r < 4; r++) {
                        int row = 32 * (wv - 2) + 16 * i + q * 4 + r;
                        vv[row * 136 + nt * 16 + ln] = f2bs(acc[i][nt][r] + bias[i][r]);
                    }
        }
        __syncthreads();

        // GEMM2: S[kc][e] += ek(64xK=128) @ vv^T
        #pragma unroll
        for (int k0 = 0; k0 < 128; k0 += 32) {
            sfrag8 a = *(const sfrag8*)(ek + (16 * wv + ln) * 136 + k0 + q * 8);
            #pragma unroll
            for (int nt = 0; nt < 4; nt++) {
                sfrag8 b = *(const sfrag8*)(vv + (nt * 16 + ln) * 136 + k0 + q * 8);
                Sacc[nt] = __builtin_amdgcn_mfma_f32_16x16x32_bf16(a, b, Sacc[nt], 0, 0, 0);
            }
        }
        // Z partials from ek (threads 0..63 each own one kc row)
        if (tid < 64) {
            #pragma unroll
            for (int c8 = 0; c8 < 16; c8++) {
                const ushort_t* p = ek + tid * 136 + c8 * 8;
                #pragma unroll
                for (int j = 0; j < 8; j++) zsum += b2f(p[j]);
            }
        }
    }

    float* Sh = S + h * 4096;
    #pragma unroll
    for (int nt = 0; nt < 4; nt++)
        #pragma unroll
        for (int r = 0; r < 4; r++) {
            int kc = 16 * wv + q * 4 + r;
            atomicAdd(&Sh[kc * 64 + nt * 16 + ln], Sacc[nt][r]);
        }
    if (tid < 64) atomicAdd(&Z[h * 64 + tid], zsum);
}

// W3B bf16 [d][c]
__global__ void k_w3t_new(const float* __restrict__ w_qkv, const float* __restrict__ W2,
                          const float* __restrict__ A, ushort_t* __restrict__ W3B) {
    int d = blockIdx.x;
    int c = threadIdx.x;
    const float* W2d = W2 + (size_t)d * HID;
    float s = 0.f;
    for (int hc = 0; hc < HID; hc++)
        s += W2d[hc] * w_qkv[(size_t)hc * DIM + c];
    W3B[(size_t)d * 256 + c] = f2bs(s * A[c]);
}

// out = W3B @ xT + b3, MFMA. grid 512: m0=(bid&1)*128, l0=(bid>>1)*128
__global__ __launch_bounds__(256) void k_final_new(const ushort_t* __restrict__ XT,
                                                   const ushort_t* __restrict__ W3B,
                                                   const float* __restrict__ B3,
                                                   float* __restrict__ out) {
    const int tid  = threadIdx.x;
    const int lane = tid & 63;
    const int wv   = __builtin_amdgcn_readfirstlane(tid >> 6);
    const int q    = lane >> 4;
    const int ln   = lane & 15;
    const int m0   = (blockIdx.x & 1) * 128;
    const int l0   = (blockIdx.x >> 1) * 128;

    const ushort_t* a0p = W3B + (size_t)(m0 + 32 * wv + ln) * 256 + q * 8;
    const ushort_t* a1p = a0p + 16 * 256;
    const ushort_t* Bb  = XT + (size_t)l0 * 256;

    f32x4 acc[2][8];
    #pragma unroll
    for (int i = 0; i < 2; i++)
        #pragma unroll
        for (int nt = 0; nt < 8; nt++)
            #pragma unroll
            for (int e = 0; e < 4; e++) acc[i][nt][e] = 0.f;

    #pragma unroll
    for (int k0 = 0; k0 < 256; k0 += 32) {
        sfrag8 a0 = *(const sfrag8*)(a0p + k0);
        sfrag8 a1 = *(const sfrag8*)(a1p + k0);
        #pragma unroll
        for (int nt = 0; nt < 8; nt++) {
            sfrag8 b = *(const sfrag8*)(Bb + (size_t)(nt * 16 + ln) * 256 + k0 + q * 8);
            acc[0][nt] = __builtin_amdgcn_mfma_f32_16x16x32_bf16(a0, b, acc[0][nt], 0, 0, 0);
            acc[1][nt] = __builtin_amdgcn_mfma_f32_16x16x32_bf16(a1, b, acc[1][nt], 0, 0, 0);
        }
    }

    float b3v[2][4];
    #pragma unroll
    for (int i = 0; i < 2; i++)
        #pragma unroll
        for (int r = 0; r < 4; r++)
            b3v[i][r] = B3[m0 + 32 * wv + 16 * i + q * 4 + r];

    #pragma unroll
    for (int i = 0; i < 2; i++)
        #pragma unroll
        for (int nt = 0; nt < 8; nt++)
            #pragma unroll
            for (int r = 0; r < 4; r++) {
                int row = m0 + 32 * wv + 16 * i + q * 4 + r;
                out[(size_t)row * LSEQ + l0 + nt * 16 + ln] = acc[i][nt][r] + b3v[i][r];
            }
}

// ======================= OLD fallback path (round-1, pointerized) =======================

#define CW   64
#define EKS  68
#define VS   68

__global__ void k_fold_w_old(const float* __restrict__ w_qkv, const float* __restrict__ A,
                             float* __restrict__ WET) {
    int idx = blockIdx.x * 256 + threadIdx.x;
    for (int i = idx; i < 1024*DIM; i += 65536) {
        int c = i >> 10, r = i & 1023;
        WET[i] = w_qkv[(size_t)(512 + r) * DIM + c] * A[c];
    }
}

__global__ __launch_bounds__(256) void k_main_old(const float* __restrict__ x,
                                                  const float* __restrict__ WET,
                                                  const float* __restrict__ BE,
                                                  float* __restrict__ Sg, float* __restrict__ Zg) {
    __shared__ __hip_bfloat16 xs[DIM*CW];
    __shared__ float ekl[DHEAD*EKS];
    __shared__ __hip_bfloat16 vsl[DHEAD*VS];
    const int tid  = threadIdx.x;
    const int col0 = blockIdx.x * CW;
    {
        const float4* x4 = (const float4*)x;
        int c4 = col0 >> 2;
        for (int i = tid; i < DIM*(CW/4); i += 256) {
            int row = i >> 4, qq = i & 15;
            float4 v = x4[(size_t)row*(LSEQ/4) + c4 + qq];
            int b = row*CW + qq*4;
            xs[b+0] = __float2bfloat16(v.x); xs[b+1] = __float2bfloat16(v.y);
            xs[b+2] = __float2bfloat16(v.z); xs[b+3] = __float2bfloat16(v.w);
        }
    }
    __syncthreads();
    const int col = tid & 63;
    const int rq  = __builtin_amdgcn_readfirstlane(tid >> 6);

    for (int h = 0; h < HEADS; h++) {
        const int base = (rq < 2) ? (h*64 + rq*32) : (512 + h*64 + (rq-2)*32);
        float acc[32];
        #pragma unroll
        for (int j = 0; j < 32; j++) acc[j] = 0.f;
        for (int c = 0; c < DIM; c++) {
            float xv = __bfloat162float(xs[c*CW + col]);
            const float* w = WET + c*1024 + base;
            #pragma unroll
            for (int j = 0; j < 32; j++) acc[j] += w[j] * xv;
        }
        __syncthreads();
        if (rq < 2) {
            const int r0 = rq*32;
            #pragma unroll
            for (int j = 0; j < 32; j++)
                ekl[(r0+j)*EKS + col] = __expf(acc[j] + BE[512 + base + j]);
        } else {
            const int r0 = (rq-2)*32;
            #pragma unroll
            for (int j = 0; j < 32; j++)
                vsl[(r0+j)*VS + col] = __float2bfloat16(acc[j] + BE[512 + base + j]);
        }
        __syncthreads();
        {
            const int c0 = tid >> 4;
            const int e0 = tid & 15;
            float sacc[4][4];
            #pragma unroll
            for (int i=0;i<4;i++)
              #pragma unroll
              for (int jj=0;jj<4;jj++) sacc[i][jj] = 0.f;
            for (int cq = 0; cq < CW/4; cq++) {
                float4 e4[4];
                #pragma unroll
                for (int i = 0; i < 4; i++)
                    e4[i] = *(const float4*)&ekl[(c0*4+i)*EKS + cq*4];
                float v4[4][4];
                #pragma unroll
                for (int jj = 0; jj < 4; jj++) {
                    ushort4 raw = *(const ushort4*)&vsl[(e0+16*jj)*VS + cq*4];
                    v4[jj][0] = __uint_as_float((uint_t)raw.x << 16);
                    v4[jj][1] = __uint_as_float((uint_t)raw.y << 16);
                    v4[jj][2] = __uint_as_float((uint_t)raw.z << 16);
                    v4[jj][3] = __uint_as_float((uint_t)raw.w << 16);
                }
                #pragma unroll
                for (int i = 0; i < 4; i++)
                  #pragma unroll
                  for (int jj = 0; jj < 4; jj++)
                    sacc[i][jj] += e4[i].x*v4[jj][0] + e4[i].y*v4[jj][1]
                                 + e4[i].z*v4[jj][2] + e4[i].w*v4[jj][3];
            }
            #pragma unroll
            for (int i = 0; i < 4; i++)
              #pragma unroll
              for (int jj = 0; jj < 4; jj++)
                atomicAdd(&Sg[(h*64 + c0*4+i)*64 + e0 + 16*jj], sacc[i][jj]);
            if (tid < 64) {
                float z = 0.f;
                for (int cq = 0; cq < CW/4; cq++) {
                    float4 e4 = *(const float4*)&ekl[tid*EKS + cq*4];
                    z += e4.x + e4.y + e4.z + e4.w;
                }
                atomicAdd(&Zg[h*64 + tid], z);
            }
        }
    }
}

__global__ void k_w3t_old(const float* __restrict__ w_qkv, const float* __restrict__ W2,
                          const float* __restrict__ A, float* __restrict__ W3T) {
    int d = blockIdx.x;
    int c = threadIdx.x;
    const float* W2d = W2 + (size_t)d*HID;
    float s = 0.f;
    for (int hc = 0; hc < HID; hc++)
        s += W2d[hc] * w_qkv[(size_t)hc*DIM + c];
    W3T[c*DIM + d] = s * A[c];
}

__global__ __launch_bounds__(256) void k_final_old(const float* __restrict__ x,
                                                   const float* __restrict__ W3T,
                                                   const float* __restrict__ B3,
                                                   float* __restrict__ out) {
    __shared__ float xs[DIM*CW];
    const int tid  = threadIdx.x;
    const int col0 = blockIdx.x * CW;
    {
        const float4* x4 = (const float4*)x;
        int c4 = col0 >> 2;
        for (int i = tid; i < DIM*(CW/4); i += 256) {
            int row = i >> 4, qq = i & 15;
            float4 v = x4[(size_t)row*(LSEQ/4) + c4 + qq];
            *(float4*)&xs[row*CW + qq*4] = v;
        }
    }
    __syncthreads();
    const int col   = tid & 63;
    const int rq    = __builtin_amdgcn_readfirstlane(tid >> 6);
    const int rbase = rq * 64;
    float acc[64];
    #pragma unroll
    for (int j = 0; j < 64; j++) acc[j] = 0.f;
    for (int c = 0; c < DIM; c++) {
        float xv = xs[c*CW + col];
        const float* w = W3T + c*DIM + rbase;
        #pragma unroll
        for (int j = 0; j < 64; j++) acc[j] += w[j] * xv;
    }
    #pragma unroll
    for (int j = 0; j < 64; j++)
        out[(size_t)(rbase + j)*LSEQ + col0 + col] = acc[j] + B3[rbase + j];
}

// ======================= launch =======================

extern "C" void kernel_launch(void* const* d_in, const int* in_sizes, int n_in,
                              void* d_out, int out_size, void* d_ws, size_t ws_size,
                              hipStream_t stream) {
    const float* x     = (const float*)d_in[0];
    const float* gn_w  = (const float*)d_in[1];
    const float* gn_b  = (const float*)d_in[2];
    const float* w_qkv = (const float*)d_in[3];
    const float* b_qkv = (const float*)d_in[4];
    const float* w_out = (const float*)d_in[5];
    const float* b_out = (const float*)d_in[6];
    float* out = (float*)d_out;
    float* ws  = (float*)d_ws;

    // shared offsets
    float* gsum   = ws + 0;         // 32
    float* gsumsq = ws + 32;        // 32
    float* S      = ws + 64;        // 32768
    float* Z      = ws + 32832;     // 512
    float* A      = ws + 33344;     // 256
    float* BB     = ws + 33600;     // 256
    float* BE     = ws + 33856;     // 1536

    hipMemsetAsync(ws, 0, 33344 * sizeof(float), stream);   // gsum..Z

    const size_t NEED_NEW = 18234624ull;   // bytes for the MFMA path
    if (ws_size >= NEED_NEW) {
        float*    BE2 = ws + 35392;                       // 1024
        ushort_t* WEB = (ushort_t*)(ws + 36416);          // 1024*256 bf16
        float*    C   = ws + 167488;                      // 32768
        float*    W2  = ws + 200256;                      // 131072
        ushort_t* W3B = (ushort_t*)(ws + 331328);         // 256*256 bf16
        float*    B3  = ws + 364096;                      // 256
        ushort_t* XT  = (ushort_t*)(ws + 364352);         // 32768*256 bf16

        k_stats     <<<DIM,  256, 0, stream>>>(x, gsum, gsumsq);
        k_tr        <<<512,  256, 0, stream>>>(x, XT);
        k_ab        <<<1,    256, 0, stream>>>(gn_w, gn_b, gsum, gsumsq, A, BB);
        k_fold_b    <<<6,    256, 0, stream>>>(w_qkv, b_qkv, BB, BE);
        k_fold_w_new<<<1024, 256, 0, stream>>>(w_qkv, A, BE, WEB, BE2);
        k_attn      <<<1024, 256, 0, stream>>>(XT, WEB, BE2, S, Z);
        k_ctx       <<<128,  256, 0, stream>>>(S, Z, C);
        k_w2        <<<512,  256, 0, stream>>>(w_out, C, W2);
        k_w3t_new   <<<256,  256, 0, stream>>>(w_qkv, W2, A, W3B);
        k_b3        <<<1,    256, 0, stream>>>(b_out, W2, BE, B3);
        k_final_new <<<512,  256, 0, stream>>>(XT, W3B, B3, out);
    } else {
        float* WET = ws + 35392;                          // 262144
        float* C   = ws + 297536;                         // 32768
        float* W2  = ws + 330304;                         // 131072
        float* W3T = ws + 461376;                         // 65536
        float* B3  = ws + 526912;                         // 256

        k_stats     <<<DIM,     256, 0, stream>>>(x, gsum, gsumsq);
        k_ab        <<<1,       256, 0, stream>>>(gn_w, gn_b, gsum, gsumsq, A, BB);
        k_fold_w_old<<<256,     256, 0, stream>>>(w_qkv, A, WET);
        k_fold_b    <<<6,       256, 0, stream>>>(w_qkv, b_qkv, BB, BE);
        k_main_old  <<<LSEQ/CW, 256, 0, stream>>>(x, WET, BE, S, Z);
        k_ctx       <<<128,     256, 0, stream>>>(S, Z, C);
        k_w2        <<<512,     256, 0, stream>>>(w_out, C, W2);
        k_w3t_old   <<<256,     256, 0, stream>>>(w_qkv, W2, A, W3T);
        k_b3        <<<1,       256, 0, stream>>>(b_out, W2, BE, B3);
        k_final_old <<<LSEQ/CW, 256, 0, stream>>>(x, W3T, B3, out);
    }
}